// Round 4
// baseline (282.170 us; speedup 1.0000x reference)
//
#include <hip/hip_runtime.h>
#include <math.h>

#define BS 16
#define QN 900
#define NC 92
#define TN 100
#define NQ (BS * QN)        // 14400
#define NT (BS * TN)        // 1600
#define C_ELEMS ((size_t)NQ * NT)  // 23,040,000
#define NK 15               // ceil(900/64) columns owned per lane
#define ARR_CAP 800         // max ARR scans (safety; expected ~40-80)

// ---------------------------------------------------------------------------
// cost of matching pred (cxcywh pb, class prob p_cls) with target (xyxy tb)
// ---------------------------------------------------------------------------
__device__ __forceinline__ float cost_entry(float4 pb, float p_cls, float4 tb) {
    float tcx = (tb.x + tb.z) * 0.5f;
    float tcy = (tb.y + tb.w) * 0.5f;
    float tw  = tb.z - tb.x;
    float th  = tb.w - tb.y;
    float cb = fabsf(pb.x - tcx) + fabsf(pb.y - tcy);
    cb += fabsf(pb.z - tw);
    cb += fabsf(pb.w - th);
    float ax0 = pb.x - pb.z * 0.5f;
    float ay0 = pb.y - pb.w * 0.5f;
    float ax1 = pb.x + pb.z * 0.5f;
    float ay1 = pb.y + pb.w * 0.5f;
    float area_a = (ax1 - ax0) * (ay1 - ay0);
    float area_b = (tb.z - tb.x) * (tb.w - tb.y);
    float ltx = fmaxf(ax0, tb.x), lty = fmaxf(ay0, tb.y);
    float rbx = fminf(ax1, tb.z), rby = fminf(ay1, tb.w);
    float iw = fmaxf(rbx - ltx, 0.0f), ih = fmaxf(rby - lty, 0.0f);
    float inter = iw * ih;
    float uni = area_a + area_b - inter;
    float iou = inter / uni;
    float cx0 = fminf(ax0, tb.x), cy0 = fminf(ay0, tb.y);
    float cx1 = fmaxf(ax1, tb.z), cy1 = fmaxf(ay1, tb.w);
    float cw = fmaxf(cx1 - cx0, 0.0f), chh = fmaxf(cy1 - cy0, 0.0f);
    float area_c = cw * chh;
    float giou = iou - (area_c - uni) / area_c;
    return (5.0f * cb - p_cls) + 2.0f * (-giou);
}

// lexicographic (value, index) min across 64 lanes; result in all lanes
__device__ __forceinline__ void wave_argmin(float& lv, int& li) {
    for (int off = 1; off < 64; off <<= 1) {
        float ov = __shfl_xor(lv, off);
        int oi = __shfl_xor(li, off);
        if (ov < lv || (ov == lv && oi < li)) { lv = ov; li = oi; }
    }
}

// (min,argmin) lexicographic + 2nd-min VALUE across 64 lanes; result in all lanes
__device__ __forceinline__ void wave_argmin2(float& m1, int& a1, float& m2) {
    for (int off = 1; off < 64; off <<= 1) {
        float b1 = __shfl_xor(m1, off);
        int bi = __shfl_xor(a1, off);
        float b2 = __shfl_xor(m2, off);
        if (b1 < m1 || (b1 == m1 && bi < a1)) {
            m2 = fminf(b2, m1);  // old min becomes 2nd-min candidate
            m1 = b1; a1 = bi;
        } else {
            m2 = fminf(m2, b1);
        }
    }
}

// ---------------------------------------------------------------------------
// Kernel A: fused softmax + full cost matrix C (float4 stores). Wave per query.
// ---------------------------------------------------------------------------
__global__ __launch_bounds__(256) void softmax_cost_kernel(
        const float* __restrict__ logits,
        const float4* __restrict__ pboxes,
        const int4* __restrict__ tids4,
        const float4* __restrict__ tbox,
        float* __restrict__ C) {
    __shared__ float shp[4][NC];
    int wid = threadIdx.x >> 6;
    int lane = threadIdx.x & 63;
    int q = blockIdx.x * 4 + wid;
    const float* row = logits + (size_t)q * NC;
    float x0 = (lane < NC) ? row[lane] : -INFINITY;
    float x1 = (lane + 64 < NC) ? row[lane + 64] : -INFINITY;
    float m = fmaxf(x0, x1);
    for (int off = 32; off; off >>= 1) m = fmaxf(m, __shfl_xor(m, off));
    float e0 = (lane < NC) ? expf(x0 - m) : 0.0f;
    float e1 = (lane + 64 < NC) ? expf(x1 - m) : 0.0f;
    float s = e0 + e1;
    for (int off = 32; off; off >>= 1) s += __shfl_xor(s, off);
    if (lane < NC) shp[wid][lane] = e0 / s;
    if (lane + 64 < NC) shp[wid][lane + 64] = e1 / s;
    __syncthreads();
    float4 pb = pboxes[q];
    float4* crow4 = (float4*)(C + (size_t)q * NT);
    for (int t4 = lane; t4 < NT / 4; t4 += 64) {
        int4 id = tids4[t4];
        int t = t4 * 4;
        float4 r;
        r.x = cost_entry(pb, shp[wid][id.x], tbox[t]);
        r.y = cost_entry(pb, shp[wid][id.y], tbox[t + 1]);
        r.z = cost_entry(pb, shp[wid][id.z], tbox[t + 2]);
        r.w = cost_entry(pb, shp[wid][id.w], tbox[t + 3]);
        crow4[t4] = r;
    }
}

// ---------------------------------------------------------------------------
// Kernel B: transpose C's per-batch diagonal 900x100 block -> cost_t[b][tt][q].
// ---------------------------------------------------------------------------
__global__ __launch_bounds__(256) void diag_transpose_kernel(
        const float* __restrict__ C, float* __restrict__ cost_t) {
    __shared__ float tile[64][65];
    int b = blockIdx.x;
    int q0 = blockIdx.y * 64;
    int t0 = blockIdx.z * 64;
    int tx = threadIdx.x & 63;
    int ty = threadIdx.x >> 6;
    for (int r = ty; r < 64; r += 4) {
        int q = q0 + r, t = t0 + tx;
        if (q < QN && t < TN)
            tile[r][tx] = C[(size_t)(b * QN + q) * NT + b * TN + t];
    }
    __syncthreads();
    for (int r = ty; r < 64; r += 4) {
        int t = t0 + r, q = q0 + tx;
        if (q < QN && t < TN)
            cost_t[(size_t)(b * TN + t) * QN + q] = tile[tx][r];
    }
}

// ---------------------------------------------------------------------------
// Kernel B2: per-row (min, argmin) of cost_t. One wave per (b,tt).
// ---------------------------------------------------------------------------
__global__ __launch_bounds__(64) void rowmin_kernel(
        const float* __restrict__ cost_t,
        float* __restrict__ rowmin, int* __restrict__ rowarg) {
    int tg = blockIdx.x;
    int lane = threadIdx.x;
    const float* row = cost_t + (size_t)tg * QN;
    float lv = INFINITY; int li = 0x7fffffff;
    #pragma unroll
    for (int k = 0; k < NK; ++k) {
        int c = lane + (k << 6);
        if (c < QN) {
            float v = row[c];
            if (v < lv) { lv = v; li = c; }
        }
    }
    wave_argmin(lv, li);
    if (lane == 0) { rowmin[tg] = lv; rowarg[tg] = li; }
}

// ---------------------------------------------------------------------------
// Kernel C: exact Hungarian. Greedy init -> JV augmenting-row-reduction (ARR)
// -> shortest-augmenting-path Dijkstra for leftovers. One wave per batch.
// Invariant throughout: duals (u,v) feasible (reduced costs >= 0), matched
// pairs tight => any completion is THE optimal assignment (unique a.s.).
// ---------------------------------------------------------------------------
__global__ __launch_bounds__(64) void lsa_kernel(
        const float* __restrict__ cost_t,
        const float* __restrict__ rowmin,
        const int* __restrict__ rowarg,
        float* __restrict__ out) {
    int b = blockIdx.x;
    int lane = threadIdx.x;
    const float* cst = cost_t + (size_t)b * TN * QN;
    __shared__ float u_s[TN + 1];
    __shared__ int p_s[QN + 1];      // column -> row (0 = free)
    __shared__ int way_s[QN + 1];
    __shared__ int x_s[TN + 1];      // row -> column (0 = unmatched)
    __shared__ int unm[TN];
    __shared__ int queue_s[1024];
    float v_r[NK], minv_r[NK], rowc[NK], rown[NK];
    int pj_r[NK];
    unsigned used_mask;

    #pragma unroll
    for (int k = 0; k < NK; ++k) v_r[k] = 0.0f;
    for (int j = lane; j <= QN; j += 64) p_s[j] = 0x7fffffff;  // sentinel: free
    if (lane == 0) { u_s[0] = 0.0f; x_s[0] = 0; }
    int jst0 = 0, jst1 = 0;
    for (int i = lane; i < TN; i += 64) {
        u_s[i + 1] = rowmin[b * TN + i];
        int js = rowarg[b * TN + i] + 1;
        if (i < 64) jst0 = js; else jst1 = js;
    }
    __syncthreads();
    // greedy: column j taken by min row index among rows whose argmin is j
    if (lane < TN) atomicMin(&p_s[jst0], lane + 1);
    if (lane + 64 < TN) atomicMin(&p_s[jst1], lane + 64 + 1);
    __syncthreads();
    if (lane < TN) x_s[lane + 1] = (p_s[jst0] == lane + 1) ? jst0 : 0;
    if (lane + 64 < TN) x_s[lane + 65] = (p_s[jst1] == lane + 65) ? jst1 : 0;
    // initial ARR queue = unmatched rows, ascending
    int head = 0, tail = 0;
    {
        bool um0 = (lane < TN) && (p_s[jst0] != lane + 1);
        unsigned long long m0 = __ballot(um0);
        if (um0) queue_s[__popcll(m0 & ((1ull << lane) - 1ull))] = lane + 1;
        tail = __popcll(m0);
        bool um1 = (lane + 64 < TN) && (p_s[jst1] != lane + 65);
        unsigned long long m1 = __ballot(um1);
        if (um1) queue_s[tail + __popcll(m1 & ((1ull << lane) - 1ull))] = lane + 65;
        tail += __popcll(m1);
    }
    __syncthreads();
    for (int j = lane; j <= QN; j += 64) if (p_s[j] == 0x7fffffff) p_s[j] = 0;
    __syncthreads();

    // ------------- ARR: each scan resolves one row by (possibly) stealing ----
    int iters = 0;
    while (head < tail && iters < ARR_CAP) {
        ++iters;
        int i = queue_s[head++];          // broadcast LDS read
        const float* crow = cst + (size_t)(i - 1) * QN;
        float m1v = INFINITY, m2v = INFINITY; int a1 = 0x7fffffff;
        #pragma unroll
        for (int k = 0; k < NK; ++k) {
            int c = lane + (k << 6);
            if (c < QN) {
                float r = crow[c] - v_r[k];
                if (r < m1v) { m2v = m1v; m1v = r; a1 = c; }
                else if (r < m2v) { m2v = r; }
            }
        }
        wave_argmin2(m1v, a1, m2v);
        int j1 = a1 + 1;
        int i0 = p_s[j1];                 // read BEFORE overwrite (in-order DS)
        if ((a1 & 63) == lane) v_r[a1 >> 6] -= (m2v - m1v);  // keep (i,j1) tight
        if (lane == 0) {
            p_s[j1] = i; x_s[i] = j1; u_s[i] = m2v;
            if (i0) { x_s[i0] = 0; queue_s[tail] = i0; }
        }
        if (i0) ++tail;                   // uniform across lanes
        __syncthreads();
    }

    // ------------- rebuild unmatched list from x_s ---------------------------
    int nunm = 0;
    {
        bool um0 = (lane < TN) && (x_s[lane + 1] == 0);
        unsigned long long m0 = __ballot(um0);
        if (um0) unm[__popcll(m0 & ((1ull << lane) - 1ull))] = lane + 1;
        nunm = __popcll(m0);
        bool um1 = (lane + 64 < TN) && (x_s[lane + 65] == 0);
        unsigned long long m1 = __ballot(um1);
        if (um1) unm[nunm + __popcll(m1 & ((1ull << lane) - 1ull))] = lane + 65;
        nunm += __popcll(m1);
    }
    __syncthreads();

    // ------------- Dijkstra shortest augmenting path for leftovers -----------
    for (int ui = 0; ui < nunm; ++ui) {
        int i_cur = unm[ui];
        if (lane == 0) p_s[0] = i_cur;
        used_mask = 0;
        #pragma unroll
        for (int k = 0; k < NK; ++k) minv_r[k] = INFINITY;
        int i0 = i_cur, j0 = 0;
        {
            const float* crow = cst + (size_t)(i0 - 1) * QN;
            #pragma unroll
            for (int k = 0; k < NK; ++k) {
                int c = lane + (k << 6);
                rowc[k] = (c < QN) ? crow[c] : 0.0f;
            }
        }
        while (true) {
            float ui0 = u_s[i0];
            float lv = INFINITY; int li = 0x7fffffff;
            #pragma unroll
            for (int k = 0; k < NK; ++k) {
                int c = lane + (k << 6);
                if (c < QN && !(used_mask & (1u << k))) {
                    float cur = rowc[k] - ui0 - v_r[k];
                    if (cur < minv_r[k]) { minv_r[k] = cur; way_s[c + 1] = j0; }
                    float mm = minv_r[k];
                    if (mm < lv) { lv = mm; li = c + 1; }
                }
            }
            wave_argmin(lv, li);
            float delta = lv;
            int j1 = li;
            int pj1 = p_s[j1];
            // prefetch next row; latency overlaps the dual update below
            {
                int irow = (pj1 == 0) ? i0 : pj1;
                const float* crow = cst + (size_t)(irow - 1) * QN;
                #pragma unroll
                for (int k = 0; k < NK; ++k) {
                    int c = lane + (k << 6);
                    rown[k] = (c < QN) ? crow[c] : 0.0f;
                }
            }
            #pragma unroll
            for (int k = 0; k < NK; ++k) {
                int c = lane + (k << 6);
                if (c < QN) {
                    if (used_mask & (1u << k)) { v_r[k] -= delta; u_s[pj_r[k]] += delta; }
                    else minv_r[k] -= delta;
                }
            }
            if (lane == 0) u_s[i_cur] += delta;
            {
                int c0 = j1 - 1;
                if ((c0 & 63) == lane) { int k0 = c0 >> 6; used_mask |= 1u << k0; pj_r[k0] = pj1; }
            }
            __syncthreads();
            j0 = j1;
            if (pj1 == 0) break;
            i0 = pj1;
            #pragma unroll
            for (int k = 0; k < NK; ++k) rowc[k] = rown[k];
        }
        if (lane == 0) {
            int jj = j0;
            while (jj) { int jn = way_s[jj]; p_s[jj] = p_s[jn]; jj = jn; }
        }
        __syncthreads();
    }

    // emit: matched columns ascending j == preds ascending (ballot ranking)
    float* rows = out + C_ELEMS + (size_t)b * TN;
    float* cols = out + C_ELEMS + (size_t)BS * TN + (size_t)b * TN;
    int base = 0;
    #pragma unroll
    for (int k = 0; k < NK; ++k) {
        int c = lane + (k << 6);
        int pv = (c < QN) ? p_s[c + 1] : 0;
        unsigned long long mask = __ballot(pv > 0);
        if (pv > 0) {
            int rank = base + __popcll(mask & ((1ull << lane) - 1ull));
            rows[rank] = (float)c;
            cols[rank] = (float)(pv - 1);
        }
        base += __popcll(mask);
    }
}

extern "C" void kernel_launch(void* const* d_in, const int* in_sizes, int n_in,
                              void* d_out, int out_size, void* d_ws, size_t ws_size,
                              hipStream_t stream) {
    const float* logits = (const float*)d_in[0];        // (16,900,92)
    const float4* pboxes = (const float4*)d_in[1];      // (16,900,4) cxcywh
    const int* tids = (const int*)d_in[2];              // (1600,)
    const float4* tbox = (const float4*)d_in[3];        // (1600,4) xyxy
    float* out = (float*)d_out;

    float* cost_t = (float*)d_ws;                       // BS*TN*QN floats (5.76 MB)
    float* rowmin = cost_t + (size_t)BS * TN * QN;      // NT floats
    int* rowarg = (int*)(rowmin + NT);                  // NT ints

    softmax_cost_kernel<<<NQ / 4, 256, 0, stream>>>(logits, pboxes, (const int4*)tids, tbox, out);
    diag_transpose_kernel<<<dim3(BS, 15, 2), 256, 0, stream>>>(out, cost_t);
    rowmin_kernel<<<NT, 64, 0, stream>>>(cost_t, rowmin, rowarg);
    lsa_kernel<<<BS, 64, 0, stream>>>(cost_t, rowmin, rowarg, out);
}

// Round 5
// 192.045 us; speedup vs baseline: 1.4693x; 1.4693x over previous
//
#include <hip/hip_runtime.h>
#include <math.h>

#define BS 16
#define QN 900
#define NC 92
#define TN 100
#define NQ (BS * QN)        // 14400
#define NT (BS * TN)        // 1600
#define C_ELEMS ((size_t)NQ * NT)  // 23,040,000
#define NK 15               // ceil(900/64) columns owned per lane

// ---------------------------------------------------------------------------
// sortable-uint float encoding (order-preserving, supports negatives)
// ---------------------------------------------------------------------------
__device__ __forceinline__ unsigned f32_sortable(float f) {
    unsigned u = __float_as_uint(f);
    return (u & 0x80000000u) ? ~u : (u | 0x80000000u);
}
__device__ __forceinline__ float f32_unsortable(unsigned s) {
    return __uint_as_float((s & 0x80000000u) ? (s ^ 0x80000000u) : ~s);
}

// ---------------------------------------------------------------------------
// DPP full-wave f32 min: 6 dependent VALU ops, result valid in lane 63.
// update_dpp old-preserve handles edge lanes; all values are >= 0 or +INF.
// ---------------------------------------------------------------------------
template<int CTRL>
__device__ __forceinline__ float dpp_fmin_step(float x) {
    int xi = __float_as_int(x);
    int yi = __builtin_amdgcn_update_dpp(xi, xi, CTRL, 0xF, 0xF, false);
    return fminf(x, __int_as_float(yi));
}
__device__ __forceinline__ float wave_fmin_to63(float x) {
    x = dpp_fmin_step<0x111>(x);  // row_shr:1
    x = dpp_fmin_step<0x112>(x);  // row_shr:2
    x = dpp_fmin_step<0x114>(x);  // row_shr:4
    x = dpp_fmin_step<0x118>(x);  // row_shr:8
    x = dpp_fmin_step<0x142>(x);  // row_bcast:15
    x = dpp_fmin_step<0x143>(x);  // row_bcast:31
    return x;
}

// uniform slot-select from a per-lane NK-array + readlane broadcast.
// c is wave-uniform; owner lane = c&63, slot = c>>6.
__device__ __forceinline__ int read_colreg(const int arr[NK], int c) {
    int v = 0;
    #pragma unroll
    for (int k = 0; k < NK; ++k) if (k == (c >> 6)) v = arr[k];
    return __builtin_amdgcn_readlane(v, c & 63);
}

// ---------------------------------------------------------------------------
// cost of matching pred (cxcywh pb, class prob p_cls) with target (xyxy tb)
// ---------------------------------------------------------------------------
__device__ __forceinline__ float cost_entry(float4 pb, float p_cls, float4 tb) {
    float tcx = (tb.x + tb.z) * 0.5f;
    float tcy = (tb.y + tb.w) * 0.5f;
    float tw  = tb.z - tb.x;
    float th  = tb.w - tb.y;
    float cb = fabsf(pb.x - tcx) + fabsf(pb.y - tcy);
    cb += fabsf(pb.z - tw);
    cb += fabsf(pb.w - th);
    float ax0 = pb.x - pb.z * 0.5f;
    float ay0 = pb.y - pb.w * 0.5f;
    float ax1 = pb.x + pb.z * 0.5f;
    float ay1 = pb.y + pb.w * 0.5f;
    float area_a = (ax1 - ax0) * (ay1 - ay0);
    float area_b = (tb.z - tb.x) * (tb.w - tb.y);
    float ltx = fmaxf(ax0, tb.x), lty = fmaxf(ay0, tb.y);
    float rbx = fminf(ax1, tb.z), rby = fminf(ay1, tb.w);
    float iw = fmaxf(rbx - ltx, 0.0f), ih = fmaxf(rby - lty, 0.0f);
    float inter = iw * ih;
    float uni = area_a + area_b - inter;
    float iou = inter / uni;
    float cx0 = fminf(ax0, tb.x), cy0 = fminf(ay0, tb.y);
    float cx1 = fmaxf(ax1, tb.z), cy1 = fmaxf(ay1, tb.w);
    float cw = fmaxf(cx1 - cx0, 0.0f), chh = fmaxf(cy1 - cy0, 0.0f);
    float area_c = cw * chh;
    float giou = iou - (area_c - uni) / area_c;
    return (5.0f * cb - p_cls) + 2.0f * (-giou);
}

// ---------------------------------------------------------------------------
// Kernel A: fused softmax + full cost matrix C (float4 stores). Wave per query.
// Blocks 0..6 additionally init the rowmin-u64 buffer to all-ones.
// ---------------------------------------------------------------------------
__global__ __launch_bounds__(256) void softmax_cost_kernel(
        const float* __restrict__ logits,
        const float4* __restrict__ pboxes,
        const int4* __restrict__ tids4,
        const float4* __restrict__ tbox,
        float* __restrict__ C,
        unsigned long long* __restrict__ rm) {
    if (blockIdx.x < 7) {
        int idx = blockIdx.x * 256 + threadIdx.x;
        if (idx < NT) rm[idx] = ~0ull;
    }
    __shared__ float shp[4][NC];
    int wid = threadIdx.x >> 6;
    int lane = threadIdx.x & 63;
    int q = blockIdx.x * 4 + wid;
    const float* row = logits + (size_t)q * NC;
    float x0 = (lane < NC) ? row[lane] : -INFINITY;
    float x1 = (lane + 64 < NC) ? row[lane + 64] : -INFINITY;
    float m = fmaxf(x0, x1);
    for (int off = 32; off; off >>= 1) m = fmaxf(m, __shfl_xor(m, off));
    float e0 = (lane < NC) ? expf(x0 - m) : 0.0f;
    float e1 = (lane + 64 < NC) ? expf(x1 - m) : 0.0f;
    float s = e0 + e1;
    for (int off = 32; off; off >>= 1) s += __shfl_xor(s, off);
    if (lane < NC) shp[wid][lane] = e0 / s;
    if (lane + 64 < NC) shp[wid][lane + 64] = e1 / s;
    __syncthreads();
    float4 pb = pboxes[q];
    float4* crow4 = (float4*)(C + (size_t)q * NT);
    for (int t4 = lane; t4 < NT / 4; t4 += 64) {
        int4 id = tids4[t4];
        int t = t4 * 4;
        float4 r;
        r.x = cost_entry(pb, shp[wid][id.x], tbox[t]);
        r.y = cost_entry(pb, shp[wid][id.y], tbox[t + 1]);
        r.z = cost_entry(pb, shp[wid][id.z], tbox[t + 2]);
        r.w = cost_entry(pb, shp[wid][id.w], tbox[t + 3]);
        crow4[t4] = r;
    }
}

// ---------------------------------------------------------------------------
// Kernel B: transpose C's per-batch diagonal 900x100 block -> cost_t[b][tt][q]
// AND accumulate per-target (min,argmin) via packed-u64 atomicMin
// (sortable(val)<<20 | q) — u64 min picks smallest q on value ties.
// ---------------------------------------------------------------------------
__global__ __launch_bounds__(256) void diag_transpose_kernel(
        const float* __restrict__ C, float* __restrict__ cost_t,
        unsigned long long* __restrict__ rm) {
    __shared__ float tile[64][65];
    int b = blockIdx.x;
    int q0 = blockIdx.y * 64;   // 15 q-tiles
    int t0 = blockIdx.z * 64;   // 2 t-tiles
    int tx = threadIdx.x & 63;
    int ty = threadIdx.x >> 6;
    for (int r = ty; r < 64; r += 4) {
        int q = q0 + r, t = t0 + tx;
        if (q < QN && t < TN)
            tile[r][tx] = C[(size_t)(b * QN + q) * NT + b * TN + t];
    }
    __syncthreads();
    for (int r = ty; r < 64; r += 4) {
        int t = t0 + r, q = q0 + tx;
        if (q < QN && t < TN)
            cost_t[(size_t)(b * TN + t) * QN + q] = tile[tx][r];
    }
    // per-t partial (min,argmin) over this tile's q-range; stride-65 = conflict-free
    if (threadIdx.x < 64) {
        int t = t0 + threadIdx.x;
        if (t < TN) {
            int qmax = min(64, QN - q0);
            float mv = INFINITY; int ma = 0;
            for (int r = 0; r < qmax; ++r) {
                float x = tile[r][threadIdx.x];
                if (x < mv) { mv = x; ma = q0 + r; }  // r asc => q asc: first-min
            }
            unsigned long long key =
                ((unsigned long long)f32_sortable(mv) << 20) | (unsigned)ma;
            atomicMin(&rm[b * TN + t], key);
        }
    }
}

// ---------------------------------------------------------------------------
// Kernel C: exact Hungarian (lazy shortest-augmenting-path, scipy-style dist),
// one 64-lane wave per batch, no barriers, no inner-loop LDS on the hot path:
//   - col state (v, dist, way, p, used) in col-distributed registers
//   - argmin via DPP min + ballot (sgpr-uniform result)
//   - p[j1]/u[i0] via readlane; row prefetch issued as soon as i0 is known
//   - all dual updates applied once per path end (lazy)
// ---------------------------------------------------------------------------
__global__ __launch_bounds__(64) void lsa_kernel(
        const float* __restrict__ cost_t,
        const unsigned long long* __restrict__ rm,
        float* __restrict__ out) {
    int b = blockIdx.x;
    int lane = threadIdx.x;
    const float* cst = cost_t + (size_t)b * TN * QN;
    __shared__ float u_s[TN];        // row duals (r-1 indexed)
    __shared__ int p_s[QN];          // greedy scratch: col -> row (1-based, sentinel)
    __shared__ int unm[TN];
    float v_r[NK], dist_r[NK], rowc[NK];
    int way_r[NK], pcol_r[NK], pj_r[NK];

    // --- init: decode rowmin u64, set duals -------------------------------
    #pragma unroll
    for (int k = 0; k < NK; ++k) { v_r[k] = 0.0f; pcol_r[k] = 0; }
    for (int j = lane; j < QN; j += 64) p_s[j] = 0x7fffffff;
    int arg0 = 0, arg1 = 0;
    float u0 = 0.0f, u1 = 0.0f;
    {
        unsigned long long k0 = rm[b * TN + lane];
        u0 = f32_unsortable((unsigned)(k0 >> 20));
        arg0 = (int)(k0 & 0xFFFFFu);
        u_s[lane] = u0;
        if (lane + 64 < TN) {
            unsigned long long k1 = rm[b * TN + lane + 64];
            u1 = f32_unsortable((unsigned)(k1 >> 20));
            arg1 = (int)(k1 & 0xFFFFFu);
            u_s[lane + 64] = u1;
        }
    }
    // --- greedy: column argmin taken by smallest row index ----------------
    atomicMin(&p_s[arg0], lane + 1);
    if (lane + 64 < TN) atomicMin(&p_s[arg1], lane + 65);
    int nunm = 0;
    {
        bool um0 = (p_s[arg0] != lane + 1);
        unsigned long long m0 = __ballot(um0);
        if (um0) unm[__popcll(m0 & ((1ull << lane) - 1ull))] = lane + 1;
        nunm = __popcll(m0);
        bool um1 = (lane + 64 < TN) && (p_s[arg1] != lane + 65);
        unsigned long long m1 = __ballot(um1);
        if (um1) unm[nunm + __popcll(m1 & ((1ull << lane) - 1ull))] = lane + 65;
        nunm += __popcll(m1);
    }
    #pragma unroll
    for (int k = 0; k < NK; ++k) {
        int c = lane + (k << 6);
        if (c < QN) { int pv = p_s[c]; pcol_r[k] = (pv == 0x7fffffff) ? 0 : pv; }
    }

    // --- shortest augmenting path per unmatched row -----------------------
    for (int ui = 0; ui < nunm; ++ui) {
        int i_cur = unm[ui];
        unsigned used_mask = 0;
        // load row i_cur, init dist
        {
            const float* crow = cst + (size_t)(i_cur - 1) * QN;
            float uic = __uint_as_float(__builtin_amdgcn_readlane(
                __float_as_uint((i_cur - 1) < 64 ? u0 : u1), (i_cur - 1) & 63));
            #pragma unroll
            for (int k = 0; k < NK; ++k) {
                int c = lane + (k << 6);
                rowc[k] = (c < QN) ? crow[c] : 0.0f;
                way_r[k] = -1;
                dist_r[k] = (c < QN) ? (rowc[k] - uic - v_r[k]) : INFINITY;
            }
        }
        float dfin; int jfree;
        while (true) {
            // local argmin over unused cols (c ascending => first-min kept)
            float lv = INFINITY; int li = 0x7fffffff;
            #pragma unroll
            for (int k = 0; k < NK; ++k) {
                if (!(used_mask & (1u << k))) {
                    float d = dist_r[k];
                    if (d < lv) { lv = d; li = lane + (k << 6); }
                }
            }
            // global min via DPP, argmin via ballot (lowest lane on exact tie)
            float gm = wave_fmin_to63(lv);
            float dmin = __uint_as_float(__builtin_amdgcn_readlane(__float_as_uint(gm), 63));
            unsigned long long eq = __ballot(lv == dmin);
            int winner = __ffsll(eq) - 1;
            int j1 = __builtin_amdgcn_readlane(li, winner);
            int pj1 = read_colreg(pcol_r, j1);
            if (pj1 == 0) { dfin = dmin; jfree = j1; break; }
            // mark j1 used; record its row
            if (lane == (j1 & 63)) {
                int k0 = j1 >> 6;
                used_mask |= 1u << k0;
                pj_r[k0] = pj1;
            }
            // prefetch row pj1 (latency overlaps relax bookkeeping below)
            {
                const float* crow = cst + (size_t)(pj1 - 1) * QN;
                #pragma unroll
                for (int k = 0; k < NK; ++k) {
                    int c = lane + (k << 6);
                    rowc[k] = (c < QN) ? crow[c] : 0.0f;
                }
            }
            float ui0 = __uint_as_float(__builtin_amdgcn_readlane(
                __float_as_uint((pj1 - 1) < 64 ? u0 : u1), (pj1 - 1) & 63));
            // relax from row pj1 (lazy: original duals + dmin offset)
            #pragma unroll
            for (int k = 0; k < NK; ++k) {
                int c = lane + (k << 6);
                if (c < QN && !(used_mask & (1u << k))) {
                    float nd = dmin + rowc[k] - ui0 - v_r[k];
                    if (nd < dist_r[k]) { dist_r[k] = nd; way_r[k] = j1; }
                }
            }
        }
        // dual updates (once per path): used cols j: a = dfin - dist[j]
        #pragma unroll
        for (int k = 0; k < NK; ++k) {
            if (used_mask & (1u << k)) {
                float a = dfin - dist_r[k];
                v_r[k] -= a;
                u_s[pj_r[k] - 1] += a;   // distinct rows => no LDS conflict
            }
        }
        if (lane == 0) u_s[i_cur - 1] += dfin;
        // refresh register u mirrors
        u0 = u_s[lane];
        if (lane + 64 < TN) u1 = u_s[lane + 64];
        // augment: walk way chain from the free column (all-lane uniform walk)
        {
            int jj = jfree;
            while (true) {
                int wj = read_colreg(way_r, jj);
                int pn = (wj < 0) ? i_cur : read_colreg(pcol_r, wj);
                if (lane == (jj & 63)) pcol_r[jj >> 6] = pn;
                if (wj < 0) break;
                jj = wj;
            }
        }
    }

    // --- emit: matched cols ascending == preds ascending ------------------
    float* rows = out + C_ELEMS + (size_t)b * TN;
    float* cols = out + C_ELEMS + (size_t)BS * TN + (size_t)b * TN;
    int base = 0;
    #pragma unroll
    for (int k = 0; k < NK; ++k) {
        int c = lane + (k << 6);
        int pv = (c < QN) ? pcol_r[k] : 0;
        unsigned long long mask = __ballot(pv > 0);
        if (pv > 0) {
            int rank = base + __popcll(mask & ((1ull << lane) - 1ull));
            rows[rank] = (float)c;
            cols[rank] = (float)(pv - 1);
        }
        base += __popcll(mask);
    }
}

extern "C" void kernel_launch(void* const* d_in, const int* in_sizes, int n_in,
                              void* d_out, int out_size, void* d_ws, size_t ws_size,
                              hipStream_t stream) {
    const float* logits = (const float*)d_in[0];        // (16,900,92)
    const float4* pboxes = (const float4*)d_in[1];      // (16,900,4) cxcywh
    const int* tids = (const int*)d_in[2];              // (1600,)
    const float4* tbox = (const float4*)d_in[3];        // (1600,4) xyxy
    float* out = (float*)d_out;

    float* cost_t = (float*)d_ws;                       // BS*TN*QN floats (5.76 MB)
    unsigned long long* rm =
        (unsigned long long*)(cost_t + (size_t)BS * TN * QN);  // NT u64 (8-aligned)

    softmax_cost_kernel<<<NQ / 4, 256, 0, stream>>>(logits, pboxes, (const int4*)tids, tbox, out, rm);
    diag_transpose_kernel<<<dim3(BS, 15, 2), 256, 0, stream>>>(out, cost_t, rm);
    lsa_kernel<<<BS, 64, 0, stream>>>(cost_t, rm, out);
}